// Round 1
// baseline (693.074 us; speedup 1.0000x reference)
//
#include <hip/hip_runtime.h>
#include <hip/hip_bf16.h>

#define Bb 1024
#define NN 50
#define KK 8
#define DD 128
#define CC 51

// ---------------- workspace layout (floats) ----------------
// bufA: subg (B*50*128) then X (B*51*128)
// bufB: Y (B*51*128) then H1 (B*51*128)
static constexpr size_t SZ_BCD = (size_t)Bb * CC * DD;       // 6684672
static constexpr size_t OFF_A   = 0;
static constexpr size_t OFF_B   = SZ_BCD;
static constexpr size_t OFF_SUM = 2 * SZ_BCD;                 // sum_hrt B*128
static constexpr size_t OFF_H2  = OFF_SUM + (size_t)Bb * DD;  // h2row B*128
static constexpr size_t OFF_BN  = OFF_H2 + (size_t)Bb * DD;   // 256 floats: [0..50] bn1 sum, [64..114] bn1 sq, [128] bn2 sum, [129] bn2 sq

// ---------------- K1: gathers, subg build, hrt outputs ----------------
__global__ __launch_bounds__(64) void k1_gather(
    const int* __restrict__ hrt, const int* __restrict__ neb,
    const int* __restrict__ nebr, const float* __restrict__ entW,
    const float* __restrict__ relW, float* __restrict__ subg,
    float* __restrict__ sumh, float* __restrict__ out) {
  int n = blockIdx.x;           // 0..50
  int b = blockIdx.y;
  int lane = threadIdx.x;       // 0..63 ; 2 floats per lane
  if (n < NN) {
    int e = neb[b * NN + n];
    float2 ev = ((const float2*)(entW + (size_t)e * DD))[lane];
    float rx = 0.f, ry = 0.f;
    const int* rb = nebr + ((size_t)(b * NN + n)) * KK;
#pragma unroll
    for (int k = 0; k < KK; ++k) {
      float2 rv = ((const float2*)(relW + (size_t)rb[k] * DD))[lane];
      rx += rv.x; ry += rv.y;
    }
    float2 s;
    s.x = 0.5f * (ev.x + rx * 0.125f);
    s.y = 0.5f * (ev.y + ry * 0.125f);
    ((float2*)(subg + ((size_t)(b * NN + n)) * DD))[lane] = s;
  } else {
    int hi = hrt[b * 3 + 0], ri = hrt[b * 3 + 1], ti = hrt[b * 3 + 2];
    float2 hv = ((const float2*)(entW + (size_t)hi * DD))[lane];
    float2 tv = ((const float2*)(entW + (size_t)ti * DD))[lane];
    float2 rv = ((const float2*)(relW + (size_t)ri * DD))[lane];
    ((float2*)(out + (size_t)b * DD))[lane] = hv;
    ((float2*)(out + (size_t)Bb * DD + (size_t)b * DD))[lane] = tv;
    ((float2*)(out + (size_t)2 * Bb * DD + (size_t)b * DD))[lane] = rv;
    const float inv3 = 1.f / 3.f;
    float2 s;
    s.x = (hv.x + tv.x + rv.x) * inv3;
    s.y = (hv.y + tv.y + rv.y) * inv3;
    ((float2*)(sumh + (size_t)b * DD))[lane] = s;
  }
}

// ---------------- K2: attention (kmat eliminated), softmax, Y = concat ----------------
__global__ __launch_bounds__(128) void k2_att(
    const float* __restrict__ subg, const float* __restrict__ sumh,
    const float* __restrict__ attW, const float* __restrict__ attb,
    float* __restrict__ Y) {
  int b = blockIdx.x, t = threadIdx.x;   // 128 threads
  __shared__ float ss[DD], sq[DD], sw[DD], sl[NN], sred[DD];
  float sv = sumh[(size_t)b * DD + t];
  ss[t] = sv;
  __syncthreads();
  // q[t] = att_b[t] + sum_e attW[t,e]*ss[e]
  float q = attb[t];
  const float* wr = attW + (size_t)t * DD;
#pragma unroll 4
  for (int e = 0; e < DD; ++e) q += wr[e] * ss[e];
  sq[t] = q;
  sred[t] = q * attb[t];
  __syncthreads();
  // w[t] = sum_d q[d]*attW[d,t]   (coalesced column read)
  float w = 0.f;
#pragma unroll 4
  for (int d = 0; d < DD; ++d) w += sq[d] * attW[(size_t)d * DD + t];
  sw[t] = w;
  // c = sum_d q[d]*att_b[d]
  for (int s = 64; s > 0; s >>= 1) {
    if (t < s) sred[t] += sred[t + s];
    __syncthreads();
  }
  float c = sred[0];
  // logits (sw visible: reduction loop ended with a barrier)
  if (t < NN) {
    const float* sg = subg + ((size_t)(b * NN + t)) * DD;
    float L = c;
#pragma unroll 4
    for (int e = 0; e < DD; ++e) L += sg[e] * sw[e];
    L = (L > 0.f) ? L : 0.01f * L;   // leaky_relu(0.01)
    sl[t] = L;
  }
  __syncthreads();
  float mx = -1e30f;
  for (int n = 0; n < NN; ++n) mx = fmaxf(mx, sl[n]);
  if (t < NN) sl[t] = expf(sl[t] - mx);
  __syncthreads();
  float sm = 0.f;
  for (int n = 0; n < NN; ++n) sm += sl[n];
  float inv = 1.f / sm;
  // Y row 0 = sum_hrt ; rows 1..50 = att[n]*subg[n]
  Y[((size_t)b * CC) * DD + t] = sv;
  for (int n = 0; n < NN; ++n) {
    float a = sl[n] * inv;
    Y[((size_t)(b * CC + 1 + n)) * DD + t] =
        a * subg[((size_t)(b * NN + n)) * DD + t];
  }
}

// ---------------- K3: X = Y @ gcn_W^T + gcn_b  (M=B*51, K=N=128) ----------------
#define K3_ROWS 128
#define ETILE 32
#define LDW 36   // 32 + 4 pad (16B-aligned rows, conflict-free f4 reads)
__global__ __launch_bounds__(256) void k3_gemm(
    const float* __restrict__ Y, const float* __restrict__ gcnW,
    const float* __restrict__ gcnb, float* __restrict__ X) {
  __shared__ float Wl[DD * LDW];
  __shared__ float Yl[K3_ROWS * LDW];
  int t = threadIdx.x;
  int tc = t & 15, tr = t >> 4;         // 16 x 16
  size_t row0 = (size_t)blockIdx.x * K3_ROWS;
  float bias[8];
#pragma unroll
  for (int j = 0; j < 8; ++j) bias[j] = gcnb[tc + 16 * j];
  float acc[8][8];
#pragma unroll
  for (int k = 0; k < 8; ++k)
#pragma unroll
    for (int j = 0; j < 8; ++j) acc[k][j] = 0.f;

  for (int et = 0; et < DD; et += ETILE) {
    __syncthreads();
    for (int idx = t; idx < DD * ETILE / 4; idx += 256) {
      int d = idx >> 3, e4 = idx & 7;
      ((float4*)(Wl + d * LDW))[e4] =
          ((const float4*)(gcnW + (size_t)d * DD + et))[e4];
    }
    for (int idx = t; idx < K3_ROWS * ETILE / 4; idx += 256) {
      int r = idx >> 3, e4 = idx & 7;
      ((float4*)(Yl + r * LDW))[e4] =
          ((const float4*)(Y + (row0 + r) * DD + et))[e4];
    }
    __syncthreads();
#pragma unroll
    for (int e4 = 0; e4 < ETILE / 4; ++e4) {
      float4 yv[8], wv[8];
#pragma unroll
      for (int k = 0; k < 8; ++k)
        yv[k] = ((const float4*)(Yl + (tr + 16 * k) * LDW))[e4];
#pragma unroll
      for (int j = 0; j < 8; ++j)
        wv[j] = ((const float4*)(Wl + (tc + 16 * j) * LDW))[e4];
#pragma unroll
      for (int k = 0; k < 8; ++k)
#pragma unroll
        for (int j = 0; j < 8; ++j)
          acc[k][j] += yv[k].x * wv[j].x + yv[k].y * wv[j].y +
                       yv[k].z * wv[j].z + yv[k].w * wv[j].w;
    }
  }
#pragma unroll
  for (int k = 0; k < 8; ++k) {
    size_t r = row0 + tr + 16 * k;
#pragma unroll
    for (int j = 0; j < 8; ++j)
      X[r * DD + tc + 16 * j] = acc[k][j] + bias[j];
  }
}

// ---------------- K4: H1 = relu(adj_b @ X_b), BN1 partial stats ----------------
__global__ __launch_bounds__(128) void k4_adj(
    const float* __restrict__ X, const float* __restrict__ adj,
    float* __restrict__ H1, float* __restrict__ bn1) {
  __shared__ float Xl[52 * 132];   // row 51 zeroed
  __shared__ float Al[51 * 56];    // adj rows, cols 51..55 zeroed
  int b = blockIdx.x, t = threadIdx.x;   // 128 threads
  int tc = t & 15, tr = t >> 4;          // tr 0..7
  for (int idx = t; idx < 52 * 32; idx += 128) {
    int r = idx >> 5, c4 = idx & 31;
    float4 v = make_float4(0.f, 0.f, 0.f, 0.f);
    if (r < 51) v = ((const float4*)(X + ((size_t)b * CC + r) * DD))[c4];
    ((float4*)(Xl + r * 132))[c4] = v;
  }
  for (int idx = t; idx < 51 * 56; idx += 128) {
    int i = idx / 56, j = idx - i * 56;
    Al[idx] = (j < 51) ? adj[(size_t)b * (CC * CC) + i * CC + j] : 0.f;
  }
  __syncthreads();
  float4 acc0[7], acc1[7];
#pragma unroll
  for (int k = 0; k < 7; ++k) {
    acc0[k] = make_float4(0.f, 0.f, 0.f, 0.f);
    acc1[k] = make_float4(0.f, 0.f, 0.f, 0.f);
  }
  for (int jj4 = 0; jj4 < 13; ++jj4) {
    float4 av[7];
#pragma unroll
    for (int k = 0; k < 7; ++k) {
      int i = tr + 8 * k;
      av[k] = (i < 51) ? ((const float4*)(Al + i * 56))[jj4]
                       : make_float4(0.f, 0.f, 0.f, 0.f);
    }
#pragma unroll
    for (int ee = 0; ee < 4; ++ee) {
      int jj = jj4 * 4 + ee;                   // up to 51; row 51 is zeros
      float4 x0 = ((const float4*)(Xl + jj * 132))[tc];
      float4 x1 = ((const float4*)(Xl + jj * 132))[tc + 16];
#pragma unroll
      for (int k = 0; k < 7; ++k) {
        float a = (ee == 0) ? av[k].x : (ee == 1) ? av[k].y
                  : (ee == 2) ? av[k].z : av[k].w;
        acc0[k].x += a * x0.x; acc0[k].y += a * x0.y;
        acc0[k].z += a * x0.z; acc0[k].w += a * x0.w;
        acc1[k].x += a * x1.x; acc1[k].y += a * x1.y;
        acc1[k].z += a * x1.z; acc1[k].w += a * x1.w;
      }
    }
  }
#pragma unroll
  for (int k = 0; k < 7; ++k) {
    int i = tr + 8 * k;
    if (i < 51) {
      float4 h0, h1v;
      h0.x = fmaxf(acc0[k].x, 0.f); h0.y = fmaxf(acc0[k].y, 0.f);
      h0.z = fmaxf(acc0[k].z, 0.f); h0.w = fmaxf(acc0[k].w, 0.f);
      h1v.x = fmaxf(acc1[k].x, 0.f); h1v.y = fmaxf(acc1[k].y, 0.f);
      h1v.z = fmaxf(acc1[k].z, 0.f); h1v.w = fmaxf(acc1[k].w, 0.f);
      ((float4*)(H1 + ((size_t)b * CC + i) * DD))[tc] = h0;
      ((float4*)(H1 + ((size_t)b * CC + i) * DD))[tc + 16] = h1v;
      float s = h0.x + h0.y + h0.z + h0.w + h1v.x + h1v.y + h1v.z + h1v.w;
      float qq = h0.x * h0.x + h0.y * h0.y + h0.z * h0.z + h0.w * h0.w +
                 h1v.x * h1v.x + h1v.y * h1v.y + h1v.z * h1v.z + h1v.w * h1v.w;
#pragma unroll
      for (int m = 1; m < 16; m <<= 1) {
        s += __shfl_xor(s, m);
        qq += __shfl_xor(qq, m);
      }
      if (tc == 0) {
        atomicAdd(&bn1[i], s);
        atomicAdd(&bn1[64 + i], qq);
      }
    }
  }
}

// ---------------- K6: h2row = relu(adj[:,0,:] @ BN1(H1)), BN2 partial stats ----------------
__global__ __launch_bounds__(128) void k6_row0(
    const float* __restrict__ H1, const float* __restrict__ adj,
    const float* __restrict__ bn1, const float* __restrict__ gamma,
    const float* __restrict__ beta, float* __restrict__ h2,
    float* __restrict__ bn2) {
  __shared__ float cj[52];
  __shared__ float td[64];
  __shared__ float reds[128], redq[128];
  int b = blockIdx.x, t = threadIdx.x;   // 128 threads: t == d
  const float invBD = 1.f / ((float)Bb * (float)DD);
  if (t < 64) td[t] = 0.f;
  if (t < 51) {
    float s = bn1[t], q = bn1[64 + t];
    float m = s * invBD;
    float v = fmaxf(q * invBD - m * m, 0.f);
    float inv = rsqrtf(v + 1e-5f);
    float al = gamma[t] * inv;
    float de = beta[t] - m * al;
    float a0 = adj[(size_t)b * (CC * CC) + t];   // adj[b][0][t]
    cj[t] = a0 * al;
    td[t] = a0 * de;
  }
  __syncthreads();
  float tcst = 0.f;
  for (int j = 0; j < 51; ++j) tcst += td[j];
  float acc = tcst;
  const float* hb = H1 + (size_t)b * CC * DD + t;
#pragma unroll 4
  for (int j = 0; j < 51; ++j) acc += cj[j] * hb[(size_t)j * DD];
  acc = fmaxf(acc, 0.f);
  h2[(size_t)b * DD + t] = acc;
  reds[t] = acc;
  redq[t] = acc * acc;
  __syncthreads();
  for (int s = 64; s > 0; s >>= 1) {
    if (t < s) { reds[t] += reds[t + s]; redq[t] += redq[t + s]; }
    __syncthreads();
  }
  if (t == 0) {
    atomicAdd(&bn2[0], reds[0]);
    atomicAdd(&bn2[1], redq[0]);
  }
}

// ---------------- K8: tri_em = BN2(h2row) -> out[3*B*D ..] ----------------
__global__ __launch_bounds__(256) void k8_final(
    const float* __restrict__ h2, const float* __restrict__ bn2,
    const float* __restrict__ gamma, const float* __restrict__ beta,
    float* __restrict__ out) {
  int i = blockIdx.x * 256 + threadIdx.x;   // < B*D
  const float invBD = 1.f / ((float)Bb * (float)DD);
  float m = bn2[0] * invBD;
  float v = fmaxf(bn2[1] * invBD - m * m, 0.f);
  float inv = rsqrtf(v + 1e-5f);
  out[(size_t)3 * Bb * DD + i] = (h2[i] - m) * inv * gamma[0] + beta[0];
}

extern "C" void kernel_launch(void* const* d_in, const int* in_sizes, int n_in,
                              void* d_out, int out_size, void* d_ws, size_t ws_size,
                              hipStream_t stream) {
  (void)in_sizes; (void)n_in; (void)out_size; (void)ws_size;
  const int*   hrt   = (const int*)d_in[0];
  const int*   neb   = (const int*)d_in[1];
  const int*   nebr  = (const int*)d_in[2];
  const float* adj   = (const float*)d_in[3];
  const float* entW  = (const float*)d_in[4];
  const float* relW  = (const float*)d_in[5];
  const float* attW  = (const float*)d_in[6];
  const float* attb  = (const float*)d_in[7];
  const float* gcnW  = (const float*)d_in[8];
  const float* gcnb  = (const float*)d_in[9];
  const float* gamma = (const float*)d_in[10];
  const float* beta  = (const float*)d_in[11];
  float* out = (float*)d_out;
  float* ws  = (float*)d_ws;

  float* subg = ws + OFF_A;
  float* X    = ws + OFF_A;     // overwrites subg (dead after k2)
  float* Y    = ws + OFF_B;
  float* H1   = ws + OFF_B;     // overwrites Y (dead after k3)
  float* sumh = ws + OFF_SUM;
  float* h2   = ws + OFF_H2;
  float* bn1  = ws + OFF_BN;
  float* bn2  = ws + OFF_BN + 128;

  hipMemsetAsync((void*)bn1, 0, 1024, stream);   // zero BN accumulators (256 floats)

  k1_gather<<<dim3(CC, Bb), 64, 0, stream>>>(hrt, neb, nebr, entW, relW,
                                             subg, sumh, out);
  k2_att<<<Bb, 128, 0, stream>>>(subg, sumh, attW, attb, Y);
  k3_gemm<<<(Bb * CC) / K3_ROWS, 256, 0, stream>>>(Y, gcnW, gcnb, X);
  k4_adj<<<Bb, 128, 0, stream>>>(X, adj, H1, bn1);
  k6_row0<<<Bb, 128, 0, stream>>>(H1, adj, bn1, gamma, beta, h2, bn2);
  k8_final<<<(Bb * DD) / 256, 256, 0, stream>>>(h2, bn2, gamma, beta, out);
}

// Round 2
// 522.320 us; speedup vs baseline: 1.3269x; 1.3269x over previous
//
#include <hip/hip_runtime.h>
#include <hip/hip_bf16.h>

#define Bb 1024
#define NN 50
#define KK 8
#define DD 128
#define CC 51

typedef __attribute__((ext_vector_type(8))) short short8;
typedef __attribute__((ext_vector_type(4))) float f32x4;

__device__ __forceinline__ unsigned short f2bf(float f) {
  union { float f; unsigned int u; } un; un.f = f;
  unsigned int r = un.u + 0x7fffu + ((un.u >> 16) & 1u);
  return (unsigned short)(r >> 16);
}

// ---------------- workspace layout (floats) ----------------
static constexpr size_t SZ_BCD = (size_t)Bb * CC * DD;       // 6684672
static constexpr size_t OFF_A   = 0;                          // subg then X
static constexpr size_t OFF_B   = SZ_BCD;                     // Ybf (bf16) then H1 (f32)
static constexpr size_t OFF_SUM = 2 * SZ_BCD;                 // sum_hrt B*128
static constexpr size_t OFF_H2  = OFF_SUM + (size_t)Bb * DD;  // h2row B*128
static constexpr size_t OFF_BN  = OFF_H2 + (size_t)Bb * DD;   // BN accumulators

// ---------------- K1: gathers, subg build, hrt outputs ----------------
__global__ __launch_bounds__(64) void k1_gather(
    const int* __restrict__ hrt, const int* __restrict__ neb,
    const int* __restrict__ nebr, const float* __restrict__ entW,
    const float* __restrict__ relW, float* __restrict__ subg,
    float* __restrict__ sumh, float* __restrict__ out) {
  int n = blockIdx.x;           // 0..50
  int b = blockIdx.y;
  int lane = threadIdx.x;       // 0..63 ; 2 floats per lane
  if (n < NN) {
    int e = neb[b * NN + n];
    float2 ev = ((const float2*)(entW + (size_t)e * DD))[lane];
    float rx = 0.f, ry = 0.f;
    const int* rb = nebr + ((size_t)(b * NN + n)) * KK;
#pragma unroll
    for (int k = 0; k < KK; ++k) {
      float2 rv = ((const float2*)(relW + (size_t)rb[k] * DD))[lane];
      rx += rv.x; ry += rv.y;
    }
    float2 s;
    s.x = 0.5f * (ev.x + rx * 0.125f);
    s.y = 0.5f * (ev.y + ry * 0.125f);
    ((float2*)(subg + ((size_t)(b * NN + n)) * DD))[lane] = s;
  } else {
    int hi = hrt[b * 3 + 0], ri = hrt[b * 3 + 1], ti = hrt[b * 3 + 2];
    float2 hv = ((const float2*)(entW + (size_t)hi * DD))[lane];
    float2 tv = ((const float2*)(entW + (size_t)ti * DD))[lane];
    float2 rv = ((const float2*)(relW + (size_t)ri * DD))[lane];
    ((float2*)(out + (size_t)b * DD))[lane] = hv;
    ((float2*)(out + (size_t)Bb * DD + (size_t)b * DD))[lane] = tv;
    ((float2*)(out + (size_t)2 * Bb * DD + (size_t)b * DD))[lane] = rv;
    const float inv3 = 1.f / 3.f;
    float2 s;
    s.x = (hv.x + tv.x + rv.x) * inv3;
    s.y = (hv.y + tv.y + rv.y) * inv3;
    ((float2*)(sumh + (size_t)b * DD))[lane] = s;
  }
}

// ---------------- K2: attention, softmax, Y (bf16) ----------------
__global__ __launch_bounds__(128) void k2_att(
    const float* __restrict__ subg, const float* __restrict__ sumh,
    const float* __restrict__ attW, const float* __restrict__ attb,
    unsigned short* __restrict__ Ybf) {
  int b = blockIdx.x, t = threadIdx.x;   // 128 threads
  __shared__ float ss[DD], sq[DD], sw[DD], red[DD];
  __shared__ float sl[NN];
  __shared__ float sub[NN * 129];        // subg tile, pad 129 (conflict-free row dot)
  __shared__ float chk[DD * 17];         // attW 16-col chunk, pad 17
  float sv = sumh[(size_t)b * DD + t];
  ss[t] = sv;
  // stage subg[b]: coalesced float4 global reads, scalar LDS writes
  for (int idx = t; idx < NN * 32; idx += 128) {
    int r = idx >> 5, c4 = idx & 31;
    float4 v = ((const float4*)(subg + ((size_t)b * NN + r) * DD))[c4];
    float* dst = sub + r * 129 + c4 * 4;
    dst[0] = v.x; dst[1] = v.y; dst[2] = v.z; dst[3] = v.w;
  }
  // q[t] = att_b[t] + sum_e attW[t,e]*ss[e]  via staged 16-col chunks
  float q = attb[t];
  for (int e0 = 0; e0 < DD; e0 += 16) {
    __syncthreads();
    for (int idx = t; idx < DD * 4; idx += 128) {
      int r = idx >> 2, c4 = idx & 3;
      float4 v = ((const float4*)(attW + (size_t)r * DD + e0))[c4];
      float* dst = chk + r * 17 + c4 * 4;
      dst[0] = v.x; dst[1] = v.y; dst[2] = v.z; dst[3] = v.w;
    }
    __syncthreads();
    const float* cr = chk + t * 17;
#pragma unroll
    for (int e = 0; e < 16; ++e) q += cr[e] * ss[e0 + e];
  }
  sq[t] = q;
  red[t] = q * attb[t];
  __syncthreads();
  // w[t] = sum_d q[d]*attW[d,t]   (coalesced column read, L2-hot)
  float w = 0.f;
#pragma unroll 4
  for (int d = 0; d < DD; ++d) w += sq[d] * attW[(size_t)d * DD + t];
  sw[t] = w;
  // c = q . att_b
  for (int s = 64; s > 0; s >>= 1) {
    if (t < s) red[t] += red[t + s];
    __syncthreads();
  }
  float c = red[0];
  // logits from LDS rows (pad 129 -> 2-way max)
  if (t < NN) {
    const float* sg = sub + t * 129;
    float L = c;
#pragma unroll 8
    for (int e = 0; e < DD; ++e) L += sg[e] * sw[e];
    sl[t] = (L > 0.f) ? L : 0.01f * L;
  }
  __syncthreads();
  float mx = -1e30f;
  for (int n = 0; n < NN; ++n) mx = fmaxf(mx, sl[n]);
  if (t < NN) sl[t] = expf(sl[t] - mx);
  __syncthreads();
  float sm = 0.f;
  for (int n = 0; n < NN; ++n) sm += sl[n];
  float inv = 1.f / sm;
  // Y row 0 = sum_hrt (bf16)
  Ybf[(size_t)b * CC * DD + t] = f2bf(sv);
  // rows 1..50 = att[n]*subg[n], packed bf16x2 writes
  for (int idx = t; idx < NN * 64; idx += 128) {
    int n = idx >> 6, c2 = (idx & 63) * 2;
    float a = sl[n] * inv;
    const float* sg = sub + n * 129 + c2;
    unsigned int pk = (unsigned int)f2bf(a * sg[0]) |
                      ((unsigned int)f2bf(a * sg[1]) << 16);
    *(unsigned int*)(Ybf + ((size_t)(b * CC + 1 + n)) * DD + c2) = pk;
  }
}

// ---------------- K3: X = Y @ gcn_W^T + gcn_b  via bf16 MFMA ----------------
#define LDK 136   // bf16 elems per LDS row (128 + 8 pad; 272 B, 16B-aligned)
__global__ __launch_bounds__(256) void k3_gemm(
    const unsigned short* __restrict__ Ybf, const float* __restrict__ gcnW,
    const float* __restrict__ gcnb, float* __restrict__ X) {
  __shared__ unsigned short Al[128 * LDK];
  __shared__ unsigned short Bl[DD * LDK];
  int t = threadIdx.x;
  size_t row0 = (size_t)blockIdx.x * 128;
  // stage A: 128 rows x 128 bf16 (2048 uint4, coalesced)
  for (int idx = t; idx < 2048; idx += 256) {
    int r = idx >> 4, c = idx & 15;
    uint4 v = ((const uint4*)(Ybf + (row0 + r) * DD))[c];
    *((uint4*)(Al + r * LDK + c * 8)) = v;
  }
  // stage B: Bl[d][e] = bf16(gcnW[d][e])  (4096 float4, coalesced)
  for (int idx = t; idx < 4096; idx += 256) {
    int d = idx >> 5, g = idx & 31;
    float4 v = ((const float4*)(gcnW + (size_t)d * DD))[g];
    ushort4 p;
    p.x = f2bf(v.x); p.y = f2bf(v.y); p.z = f2bf(v.z); p.w = f2bf(v.w);
    *((ushort4*)(Bl + d * LDK + g * 4)) = p;
  }
  __syncthreads();
  int wv = t >> 6, lane = t & 63;
  int m16 = lane & 15;
  int q8 = (lane >> 4) * 8;
  f32x4 acc[2][8] = {};
  const unsigned short* Abase = Al + (wv * 32 + m16) * LDK + q8;
  const unsigned short* Bbase = Bl + m16 * LDK + q8;
#pragma unroll
  for (int ks = 0; ks < 4; ++ks) {
    short8 a0 = *(const short8*)(Abase + ks * 32);
    short8 a1 = *(const short8*)(Abase + 16 * LDK + ks * 32);
#pragma unroll
    for (int nt = 0; nt < 8; ++nt) {
      short8 bb = *(const short8*)(Bbase + nt * 16 * LDK + ks * 32);
      acc[0][nt] = __builtin_amdgcn_mfma_f32_16x16x32_bf16(a0, bb, acc[0][nt], 0, 0, 0);
      acc[1][nt] = __builtin_amdgcn_mfma_f32_16x16x32_bf16(a1, bb, acc[1][nt], 0, 0, 0);
    }
  }
  // epilogue: C/D layout col=lane&15, row=(lane>>4)*4+reg
  int qd = (lane >> 4) * 4;
#pragma unroll
  for (int rt = 0; rt < 2; ++rt) {
#pragma unroll
    for (int nt = 0; nt < 8; ++nt) {
      float bias = gcnb[nt * 16 + m16];
#pragma unroll
      for (int r = 0; r < 4; ++r) {
        size_t grow = row0 + wv * 32 + rt * 16 + qd + r;
        X[grow * DD + nt * 16 + m16] = acc[rt][nt][r] + bias;
      }
    }
  }
}

// ---------------- K4: H1 = relu(adj_b @ X_b), BN1 partial stats ----------------
__global__ __launch_bounds__(128) void k4_adj(
    const float* __restrict__ X, const float* __restrict__ adj,
    float* __restrict__ H1, float* __restrict__ bn1) {
  __shared__ float Xl[52 * 132];   // row 51 zeroed
  __shared__ float Al[51 * 56];    // adj rows, cols 51..55 zeroed
  int b = blockIdx.x, t = threadIdx.x;   // 128 threads
  int tc = t & 15, tr = t >> 4;          // tr 0..7
  for (int idx = t; idx < 52 * 32; idx += 128) {
    int r = idx >> 5, c4 = idx & 31;
    float4 v = make_float4(0.f, 0.f, 0.f, 0.f);
    if (r < 51) v = ((const float4*)(X + ((size_t)b * CC + r) * DD))[c4];
    ((float4*)(Xl + r * 132))[c4] = v;
  }
  for (int idx = t; idx < 51 * 56; idx += 128) {
    int i = idx / 56, j = idx - i * 56;
    Al[idx] = (j < 51) ? adj[(size_t)b * (CC * CC) + i * CC + j] : 0.f;
  }
  __syncthreads();
  float4 acc0[7], acc1[7];
#pragma unroll
  for (int k = 0; k < 7; ++k) {
    acc0[k] = make_float4(0.f, 0.f, 0.f, 0.f);
    acc1[k] = make_float4(0.f, 0.f, 0.f, 0.f);
  }
  for (int jj4 = 0; jj4 < 13; ++jj4) {
    float4 av[7];
#pragma unroll
    for (int k = 0; k < 7; ++k) {
      int i = tr + 8 * k;
      av[k] = (i < 51) ? ((const float4*)(Al + i * 56))[jj4]
                       : make_float4(0.f, 0.f, 0.f, 0.f);
    }
#pragma unroll
    for (int ee = 0; ee < 4; ++ee) {
      int jj = jj4 * 4 + ee;                   // up to 51; row 51 is zeros
      float4 x0 = ((const float4*)(Xl + jj * 132))[tc];
      float4 x1 = ((const float4*)(Xl + jj * 132))[tc + 16];
#pragma unroll
      for (int k = 0; k < 7; ++k) {
        float a = (ee == 0) ? av[k].x : (ee == 1) ? av[k].y
                  : (ee == 2) ? av[k].z : av[k].w;
        acc0[k].x += a * x0.x; acc0[k].y += a * x0.y;
        acc0[k].z += a * x0.z; acc0[k].w += a * x0.w;
        acc1[k].x += a * x1.x; acc1[k].y += a * x1.y;
        acc1[k].z += a * x1.z; acc1[k].w += a * x1.w;
      }
    }
  }
#pragma unroll
  for (int k = 0; k < 7; ++k) {
    int i = tr + 8 * k;
    if (i < 51) {
      float4 h0, h1v;
      h0.x = fmaxf(acc0[k].x, 0.f); h0.y = fmaxf(acc0[k].y, 0.f);
      h0.z = fmaxf(acc0[k].z, 0.f); h0.w = fmaxf(acc0[k].w, 0.f);
      h1v.x = fmaxf(acc1[k].x, 0.f); h1v.y = fmaxf(acc1[k].y, 0.f);
      h1v.z = fmaxf(acc1[k].z, 0.f); h1v.w = fmaxf(acc1[k].w, 0.f);
      ((float4*)(H1 + ((size_t)b * CC + i) * DD))[tc] = h0;
      ((float4*)(H1 + ((size_t)b * CC + i) * DD))[tc + 16] = h1v;
      float s = h0.x + h0.y + h0.z + h0.w + h1v.x + h1v.y + h1v.z + h1v.w;
      float qq = h0.x * h0.x + h0.y * h0.y + h0.z * h0.z + h0.w * h0.w +
                 h1v.x * h1v.x + h1v.y * h1v.y + h1v.z * h1v.z + h1v.w * h1v.w;
#pragma unroll
      for (int m = 1; m < 16; m <<= 1) {
        s += __shfl_xor(s, m);
        qq += __shfl_xor(qq, m);
      }
      if (tc == 0) {
        atomicAdd(&bn1[i], s);
        atomicAdd(&bn1[64 + i], qq);
      }
    }
  }
}

// ---------------- K6: h2row = relu(adj[:,0,:] @ BN1(H1)), BN2 partial stats ----------------
__global__ __launch_bounds__(128) void k6_row0(
    const float* __restrict__ H1, const float* __restrict__ adj,
    const float* __restrict__ bn1, const float* __restrict__ gamma,
    const float* __restrict__ beta, float* __restrict__ h2,
    float* __restrict__ bn2) {
  __shared__ float cj[52];
  __shared__ float td[64];
  __shared__ float reds[128], redq[128];
  int b = blockIdx.x, t = threadIdx.x;   // 128 threads: t == d
  const float invBD = 1.f / ((float)Bb * (float)DD);
  if (t < 64) td[t] = 0.f;
  if (t < 51) {
    float s = bn1[t], q = bn1[64 + t];
    float m = s * invBD;
    float v = fmaxf(q * invBD - m * m, 0.f);
    float inv = rsqrtf(v + 1e-5f);
    float al = gamma[t] * inv;
    float de = beta[t] - m * al;
    float a0 = adj[(size_t)b * (CC * CC) + t];   // adj[b][0][t]
    cj[t] = a0 * al;
    td[t] = a0 * de;
  }
  __syncthreads();
  float tcst = 0.f;
  for (int j = 0; j < 51; ++j) tcst += td[j];
  float acc = tcst;
  const float* hb = H1 + (size_t)b * CC * DD + t;
#pragma unroll 4
  for (int j = 0; j < 51; ++j) acc += cj[j] * hb[(size_t)j * DD];
  acc = fmaxf(acc, 0.f);
  h2[(size_t)b * DD + t] = acc;
  reds[t] = acc;
  redq[t] = acc * acc;
  __syncthreads();
  for (int s = 64; s > 0; s >>= 1) {
    if (t < s) { reds[t] += reds[t + s]; redq[t] += redq[t + s]; }
    __syncthreads();
  }
  if (t == 0) {
    atomicAdd(&bn2[0], reds[0]);
    atomicAdd(&bn2[1], redq[0]);
  }
}

// ---------------- K8: tri_em = BN2(h2row) -> out[3*B*D ..] ----------------
__global__ __launch_bounds__(256) void k8_final(
    const float* __restrict__ h2, const float* __restrict__ bn2,
    const float* __restrict__ gamma, const float* __restrict__ beta,
    float* __restrict__ out) {
  int i = blockIdx.x * 256 + threadIdx.x;   // < B*D
  const float invBD = 1.f / ((float)Bb * (float)DD);
  float m = bn2[0] * invBD;
  float v = fmaxf(bn2[1] * invBD - m * m, 0.f);
  float inv = rsqrtf(v + 1e-5f);
  out[(size_t)3 * Bb * DD + i] = (h2[i] - m) * inv * gamma[0] + beta[0];
}

extern "C" void kernel_launch(void* const* d_in, const int* in_sizes, int n_in,
                              void* d_out, int out_size, void* d_ws, size_t ws_size,
                              hipStream_t stream) {
  (void)in_sizes; (void)n_in; (void)out_size; (void)ws_size;
  const int*   hrt   = (const int*)d_in[0];
  const int*   neb   = (const int*)d_in[1];
  const int*   nebr  = (const int*)d_in[2];
  const float* adj   = (const float*)d_in[3];
  const float* entW  = (const float*)d_in[4];
  const float* relW  = (const float*)d_in[5];
  const float* attW  = (const float*)d_in[6];
  const float* attb  = (const float*)d_in[7];
  const float* gcnW  = (const float*)d_in[8];
  const float* gcnb  = (const float*)d_in[9];
  const float* gamma = (const float*)d_in[10];
  const float* beta  = (const float*)d_in[11];
  float* out = (float*)d_out;
  float* ws  = (float*)d_ws;

  float*          subg = ws + OFF_A;
  float*          X    = ws + OFF_A;     // overwrites subg (dead after k2)
  unsigned short* Ybf  = (unsigned short*)(ws + OFF_B);
  float*          H1   = ws + OFF_B;     // overwrites Ybf (dead after k3)
  float*          sumh = ws + OFF_SUM;
  float*          h2   = ws + OFF_H2;
  float*          bn1  = ws + OFF_BN;
  float*          bn2  = ws + OFF_BN + 128;

  hipMemsetAsync((void*)bn1, 0, 1024, stream);   // zero BN accumulators

  k1_gather<<<dim3(CC, Bb), 64, 0, stream>>>(hrt, neb, nebr, entW, relW,
                                             subg, sumh, out);
  k2_att<<<Bb, 128, 0, stream>>>(subg, sumh, attW, attb, Ybf);
  k3_gemm<<<(Bb * CC) / 128, 256, 0, stream>>>(Ybf, gcnW, gcnb, X);
  k4_adj<<<Bb, 128, 0, stream>>>(X, adj, H1, bn1);
  k6_row0<<<Bb, 128, 0, stream>>>(H1, adj, bn1, gamma, beta, h2, bn2);
  k8_final<<<(Bb * DD) / 256, 256, 0, stream>>>(h2, bn2, gamma, beta, out);
}

// Round 4
// 499.616 us; speedup vs baseline: 1.3872x; 1.0454x over previous
//
#include <hip/hip_runtime.h>
#include <hip/hip_bf16.h>

#define Bb 1024
#define NN 50
#define KK 8
#define DD 128
#define CC 51

typedef __attribute__((ext_vector_type(8))) short short8;
typedef __attribute__((ext_vector_type(4))) float f32x4;

__device__ __forceinline__ unsigned short f2bf(float f) {
  union { float f; unsigned int u; } un; un.f = f;
  unsigned int r = un.u + 0x7fffu + ((un.u >> 16) & 1u);
  return (unsigned short)(r >> 16);
}
__device__ __forceinline__ float bf2f(unsigned short h) {
  union { unsigned int u; float f; } un; un.u = ((unsigned int)h) << 16;
  return un.f;
}

// ---------------- workspace layout ----------------
// Ybf (bf16, B*51*128) | Xbf (bf16) | H1bf (bf16) | bn accums (f32) | h2 (f32)
static constexpr size_t SZ_BCD = (size_t)Bb * CC * DD;   // 6684672 elems
static constexpr size_t BYTES_Y  = SZ_BCD * 2;
static constexpr size_t OFF_X    = BYTES_Y;
static constexpr size_t OFF_H1   = BYTES_Y * 2;
static constexpr size_t OFF_BN   = BYTES_Y * 3;          // 256 floats

// ---------------- K12: gather + subg(LDS) + attention + Y(bf16) ----------------
__global__ __launch_bounds__(256) void k12_gatt(
    const int* __restrict__ hrt, const int* __restrict__ neb,
    const int* __restrict__ nebr, const float* __restrict__ entW,
    const float* __restrict__ relW, const float* __restrict__ attW,
    const float* __restrict__ attb, unsigned short* __restrict__ Ybf,
    float* __restrict__ out) {
  int b = blockIdx.x, t = threadIdx.x;   // 256 threads
  __shared__ float ss[DD], sq[DD], sw[DD];
  __shared__ float red[256];
  __shared__ float sl[NN];
  __shared__ float cval;
  __shared__ float sub[NN * 132];        // pad 132 (16B-aligned rows)

  // hrt gathers + sum_hrt (threads 0..31, float4 lanes)
  if (t < 32) {
    int hi = hrt[b * 3 + 0], ri = hrt[b * 3 + 1], ti = hrt[b * 3 + 2];
    float4 hv = ((const float4*)(entW + (size_t)hi * DD))[t];
    float4 tv = ((const float4*)(entW + (size_t)ti * DD))[t];
    float4 rv = ((const float4*)(relW + (size_t)ri * DD))[t];
    ((float4*)(out + (size_t)b * DD))[t] = hv;
    ((float4*)(out + (size_t)Bb * DD + (size_t)b * DD))[t] = tv;
    ((float4*)(out + (size_t)2 * Bb * DD + (size_t)b * DD))[t] = rv;
    const float inv3 = 1.f / 3.f;
    float4 s;
    s.x = (hv.x + tv.x + rv.x) * inv3;
    s.y = (hv.y + tv.y + rv.y) * inv3;
    s.z = (hv.z + tv.z + rv.z) * inv3;
    s.w = (hv.w + tv.w + rv.w) * inv3;
    ((float4*)ss)[t] = s;
  }
  // neighbor rows -> sub (LDS only)
  for (int idx = t; idx < NN * 32; idx += 256) {
    int r = idx >> 5, c4 = idx & 31;
    int e = neb[b * NN + r];
    float4 ev = ((const float4*)(entW + (size_t)e * DD))[c4];
    const int* rb = nebr + ((size_t)(b * NN + r)) * KK;
    float4 rs = make_float4(0.f, 0.f, 0.f, 0.f);
#pragma unroll
    for (int k = 0; k < KK; ++k) {
      float4 rv = ((const float4*)(relW + (size_t)rb[k] * DD))[c4];
      rs.x += rv.x; rs.y += rv.y; rs.z += rv.z; rs.w += rv.w;
    }
    float4 sg;
    sg.x = 0.5f * (ev.x + rs.x * 0.125f);
    sg.y = 0.5f * (ev.y + rs.y * 0.125f);
    sg.z = 0.5f * (ev.z + rs.z * 0.125f);
    sg.w = 0.5f * (ev.w + rs.w * 0.125f);
    ((float4*)(sub + r * 132))[c4] = sg;
  }
  __syncthreads();
  // q partials: threads t<128 do e in [0,64) for d=t; t>=128 do e in [64,128)
  {
    int d = t & 127, e0 = (t >> 7) * 64;
    const float4* wr4 = (const float4*)(attW + (size_t)d * DD + e0);
    const float4* ss4 = (const float4*)(ss + e0);
    float qp = 0.f;
#pragma unroll
    for (int i = 0; i < 16; ++i) {
      float4 wv = wr4[i], sv = ss4[i];
      qp += wv.x * sv.x + wv.y * sv.y + wv.z * sv.z + wv.w * sv.w;
    }
    red[t] = qp;
  }
  __syncthreads();
  if (t < 128) sq[t] = red[t] + red[t + 128] + attb[t];
  __syncthreads();
  // w partials: w[d] = sum_k sq[k]*attW[k][d]; halves over k (coalesced)
  {
    int d = t & 127, k0 = (t >> 7) * 64;
    float wp = 0.f;
#pragma unroll 4
    for (int k = 0; k < 64; ++k)
      wp += sq[k0 + k] * attW[(size_t)(k0 + k) * DD + d];
    red[t] = wp;
  }
  __syncthreads();
  if (t < 128) sw[t] = red[t] + red[t + 128];
  if (t < 64) {   // c = sq . attb  (wave 0 shuffle reduce)
    float v = sq[t] * attb[t] + sq[t + 64] * attb[t + 64];
#pragma unroll
    for (int m = 1; m < 64; m <<= 1) v += __shfl_xor(v, m);
    if (t == 0) cval = v;
  }
  __syncthreads();
  // logits: 4 threads per row n
  if (t < NN * 4) {
    int n = t >> 2, q = t & 3;
    const float* sg = sub + n * 132 + q * 32;
    const float* wq = sw + q * 32;
    float L = 0.f;
#pragma unroll 8
    for (int e = 0; e < 32; ++e) L += sg[e] * wq[e];
    L += __shfl_xor(L, 1);
    L += __shfl_xor(L, 2);
    if (q == 0) {
      L += cval;
      sl[n] = (L > 0.f) ? L : 0.01f * L;
    }
  }
  __syncthreads();
  // softmax over 50 (wave 0)
  if (t < 64) {
    float v = (t < NN) ? sl[t] : -1e30f;
    float mx = v;
#pragma unroll
    for (int m = 1; m < 64; m <<= 1) mx = fmaxf(mx, __shfl_xor(mx, m));
    float e = (t < NN) ? __expf(v - mx) : 0.f;
    float sm = e;
#pragma unroll
    for (int m = 1; m < 64; m <<= 1) sm += __shfl_xor(sm, m);
    if (t < NN) sl[t] = e / sm;
  }
  __syncthreads();
  // Y row 0 = sum_hrt
  if (t < 128) Ybf[(size_t)b * CC * DD + t] = f2bf(ss[t]);
  // rows 1..50 = att[n]*subg[n]
  for (int idx = t; idx < NN * 64; idx += 256) {
    int n = idx >> 6, c2 = (idx & 63) * 2;
    float a = sl[n];
    const float* sg = sub + n * 132 + c2;
    unsigned int pk = (unsigned int)f2bf(a * sg[0]) |
                      ((unsigned int)f2bf(a * sg[1]) << 16);
    *(unsigned int*)(Ybf + ((size_t)(b * CC + 1 + n)) * DD + c2) = pk;
  }
}

// ---------------- K3: X(bf16) = Y @ gcn_W^T + gcn_b  via bf16 MFMA ----------------
#define LDK 136
__global__ __launch_bounds__(256) void k3_gemm(
    const unsigned short* __restrict__ Ybf, const float* __restrict__ gcnW,
    const float* __restrict__ gcnb, unsigned short* __restrict__ Xbf) {
  __shared__ unsigned short Al[128 * LDK];
  __shared__ unsigned short Bl[DD * LDK];
  int t = threadIdx.x;
  size_t row0 = (size_t)blockIdx.x * 128;
  for (int idx = t; idx < 2048; idx += 256) {
    int r = idx >> 4, c = idx & 15;
    uint4 v = ((const uint4*)(Ybf + (row0 + r) * DD))[c];
    *((uint4*)(Al + r * LDK + c * 8)) = v;
  }
  for (int idx = t; idx < 4096; idx += 256) {
    int d = idx >> 5, g = idx & 31;
    float4 v = ((const float4*)(gcnW + (size_t)d * DD))[g];
    ushort4 p;
    p.x = f2bf(v.x); p.y = f2bf(v.y); p.z = f2bf(v.z); p.w = f2bf(v.w);
    *((ushort4*)(Bl + d * LDK + g * 4)) = p;
  }
  __syncthreads();
  int wv = t >> 6, lane = t & 63;
  int m16 = lane & 15;
  int q8 = (lane >> 4) * 8;
  f32x4 acc[2][8] = {};
  const unsigned short* Abase = Al + (wv * 32 + m16) * LDK + q8;
  const unsigned short* Bbase = Bl + m16 * LDK + q8;
#pragma unroll
  for (int ks = 0; ks < 4; ++ks) {
    short8 a0 = *(const short8*)(Abase + ks * 32);
    short8 a1 = *(const short8*)(Abase + 16 * LDK + ks * 32);
#pragma unroll
    for (int nt = 0; nt < 8; ++nt) {
      short8 bb = *(const short8*)(Bbase + nt * 16 * LDK + ks * 32);
      acc[0][nt] = __builtin_amdgcn_mfma_f32_16x16x32_bf16(a0, bb, acc[0][nt], 0, 0, 0);
      acc[1][nt] = __builtin_amdgcn_mfma_f32_16x16x32_bf16(a1, bb, acc[1][nt], 0, 0, 0);
    }
  }
  int qd = (lane >> 4) * 4;
#pragma unroll
  for (int rt = 0; rt < 2; ++rt) {
#pragma unroll
    for (int nt = 0; nt < 8; ++nt) {
      float bias = gcnb[nt * 16 + m16];
#pragma unroll
      for (int r = 0; r < 4; ++r) {
        size_t grow = row0 + wv * 32 + rt * 16 + qd + r;
        Xbf[grow * DD + nt * 16 + m16] = f2bf(acc[rt][nt][r] + bias);
      }
    }
  }
}

// ---------------- K4: H1(bf16) = relu(adj_b @ X_b), BN1 partial stats ----------------
__global__ __launch_bounds__(128) void k4_adj(
    const unsigned short* __restrict__ Xbf, const float* __restrict__ adj,
    unsigned short* __restrict__ H1bf, float* __restrict__ bn1) {
  __shared__ float Xl[52 * 132];   // row 51 zeroed
  __shared__ float Al[51 * 56];
  int b = blockIdx.x, t = threadIdx.x;   // 128 threads
  int tc = t & 15, tr = t >> 4;
  for (int idx = t; idx < 52 * 16; idx += 128) {
    int r = idx >> 4, c8 = idx & 15;
    float4 lo = make_float4(0.f, 0.f, 0.f, 0.f), hi = lo;
    if (r < 51) {
      uint4 v = ((const uint4*)(Xbf + ((size_t)b * CC + r) * DD))[c8];
      lo.x = bf2f((unsigned short)(v.x & 0xffff)); lo.y = bf2f((unsigned short)(v.x >> 16));
      lo.z = bf2f((unsigned short)(v.y & 0xffff)); lo.w = bf2f((unsigned short)(v.y >> 16));
      hi.x = bf2f((unsigned short)(v.z & 0xffff)); hi.y = bf2f((unsigned short)(v.z >> 16));
      hi.z = bf2f((unsigned short)(v.w & 0xffff)); hi.w = bf2f((unsigned short)(v.w >> 16));
    }
    ((float4*)(Xl + r * 132 + c8 * 8))[0] = lo;
    ((float4*)(Xl + r * 132 + c8 * 8))[1] = hi;
  }
  for (int idx = t; idx < 51 * 56; idx += 128) {
    int i = idx / 56, j = idx - i * 56;
    Al[idx] = (j < 51) ? adj[(size_t)b * (CC * CC) + i * CC + j] : 0.f;
  }
  __syncthreads();
  float4 acc0[7], acc1[7];
#pragma unroll
  for (int k = 0; k < 7; ++k) {
    acc0[k] = make_float4(0.f, 0.f, 0.f, 0.f);
    acc1[k] = make_float4(0.f, 0.f, 0.f, 0.f);
  }
  for (int jj4 = 0; jj4 < 13; ++jj4) {
    float4 av[7];
#pragma unroll
    for (int k = 0; k < 7; ++k) {
      int i = tr + 8 * k;
      av[k] = (i < 51) ? ((const float4*)(Al + i * 56))[jj4]
                       : make_float4(0.f, 0.f, 0.f, 0.f);
    }
#pragma unroll
    for (int ee = 0; ee < 4; ++ee) {
      int jj = jj4 * 4 + ee;
      float4 x0 = ((const float4*)(Xl + jj * 132))[tc];
      float4 x1 = ((const float4*)(Xl + jj * 132))[tc + 16];
#pragma unroll
      for (int k = 0; k < 7; ++k) {
        float a = (ee == 0) ? av[k].x : (ee == 1) ? av[k].y
                  : (ee == 2) ? av[k].z : av[k].w;
        acc0[k].x += a * x0.x; acc0[k].y += a * x0.y;
        acc0[k].z += a * x0.z; acc0[k].w += a * x0.w;
        acc1[k].x += a * x1.x; acc1[k].y += a * x1.y;
        acc1[k].z += a * x1.z; acc1[k].w += a * x1.w;
      }
    }
  }
#pragma unroll
  for (int k = 0; k < 7; ++k) {
    int i = tr + 8 * k;
    if (i < 51) {
      float4 h0, h1v;
      h0.x = fmaxf(acc0[k].x, 0.f); h0.y = fmaxf(acc0[k].y, 0.f);
      h0.z = fmaxf(acc0[k].z, 0.f); h0.w = fmaxf(acc0[k].w, 0.f);
      h1v.x = fmaxf(acc1[k].x, 0.f); h1v.y = fmaxf(acc1[k].y, 0.f);
      h1v.z = fmaxf(acc1[k].z, 0.f); h1v.w = fmaxf(acc1[k].w, 0.f);
      size_t rowoff = ((size_t)b * CC + i) * DD;
      ushort4 p0, p1;
      p0.x = f2bf(h0.x); p0.y = f2bf(h0.y); p0.z = f2bf(h0.z); p0.w = f2bf(h0.w);
      p1.x = f2bf(h1v.x); p1.y = f2bf(h1v.y); p1.z = f2bf(h1v.z); p1.w = f2bf(h1v.w);
      ((ushort4*)(H1bf + rowoff))[tc] = p0;
      ((ushort4*)(H1bf + rowoff))[tc + 16] = p1;
      float s = h0.x + h0.y + h0.z + h0.w + h1v.x + h1v.y + h1v.z + h1v.w;
      float qq = h0.x * h0.x + h0.y * h0.y + h0.z * h0.z + h0.w * h0.w +
                 h1v.x * h1v.x + h1v.y * h1v.y + h1v.z * h1v.z + h1v.w * h1v.w;
#pragma unroll
      for (int m = 1; m < 16; m <<= 1) {
        s += __shfl_xor(s, m);
        qq += __shfl_xor(qq, m);
      }
      if (tc == 0) {
        atomicAdd(&bn1[i], s);
        atomicAdd(&bn1[64 + i], qq);
      }
    }
  }
}

// ---------------- K6: h2 = relu(adj0 @ BN1(H1)), BN2 partial stats ----------------
__global__ __launch_bounds__(128) void k6_row0(
    const unsigned short* __restrict__ H1bf, const float* __restrict__ adj,
    const float* __restrict__ bn1, const float* __restrict__ gamma,
    const float* __restrict__ beta, float* __restrict__ h2,
    float* __restrict__ bn2) {
  __shared__ float cj[52];
  __shared__ float td[64];
  __shared__ float reds[128], redq[128];
  int b = blockIdx.x, t = threadIdx.x;   // t == d
  const float invBD = 1.f / ((float)Bb * (float)DD);
  if (t < 64) td[t] = 0.f;
  if (t < 51) {
    float s = bn1[t], q = bn1[64 + t];
    float m = s * invBD;
    float v = fmaxf(q * invBD - m * m, 0.f);
    float inv = rsqrtf(v + 1e-5f);
    float al = gamma[t] * inv;
    float de = beta[t] - m * al;
    float a0 = adj[(size_t)b * (CC * CC) + t];
    cj[t] = a0 * al;
    td[t] = a0 * de;
  }
  __syncthreads();
  float tcst = 0.f;
  for (int j = 0; j < 51; ++j) tcst += td[j];
  float acc = tcst;
  const unsigned short* hb = H1bf + (size_t)b * CC * DD + t;
#pragma unroll 4
  for (int j = 0; j < 51; ++j) acc += cj[j] * bf2f(hb[(size_t)j * DD]);
  acc = fmaxf(acc, 0.f);
  h2[(size_t)b * DD + t] = acc;
  reds[t] = acc;
  redq[t] = acc * acc;
  __syncthreads();
  for (int s = 64; s > 0; s >>= 1) {
    if (t < s) { reds[t] += reds[t + s]; redq[t] += redq[t + s]; }
    __syncthreads();
  }
  if (t == 0) {
    atomicAdd(&bn2[0], reds[0]);
    atomicAdd(&bn2[1], redq[0]);
  }
}

// ---------------- K8: tri_em = BN2(h2) ----------------
__global__ __launch_bounds__(256) void k8_final(
    const float* __restrict__ h2, const float* __restrict__ bn2,
    const float* __restrict__ gamma, const float* __restrict__ beta,
    float* __restrict__ out) {
  int i = blockIdx.x * 256 + threadIdx.x;
  const float invBD = 1.f / ((float)Bb * (float)DD);
  float m = bn2[0] * invBD;
  float v = fmaxf(bn2[1] * invBD - m * m, 0.f);
  float inv = rsqrtf(v + 1e-5f);
  out[(size_t)3 * Bb * DD + i] = (h2[i] - m) * inv * gamma[0] + beta[0];
}

extern "C" void kernel_launch(void* const* d_in, const int* in_sizes, int n_in,
                              void* d_out, int out_size, void* d_ws, size_t ws_size,
                              hipStream_t stream) {
  (void)in_sizes; (void)n_in; (void)out_size; (void)ws_size;
  const int*   hrt   = (const int*)d_in[0];
  const int*   neb   = (const int*)d_in[1];
  const int*   nebr  = (const int*)d_in[2];
  const float* adj   = (const float*)d_in[3];
  const float* entW  = (const float*)d_in[4];
  const float* relW  = (const float*)d_in[5];
  const float* attW  = (const float*)d_in[6];
  const float* attb  = (const float*)d_in[7];
  const float* gcnW  = (const float*)d_in[8];
  const float* gcnb  = (const float*)d_in[9];
  const float* gamma = (const float*)d_in[10];
  const float* beta  = (const float*)d_in[11];
  float* out = (float*)d_out;
  char*  ws  = (char*)d_ws;

  unsigned short* Ybf  = (unsigned short*)ws;
  unsigned short* Xbf  = (unsigned short*)(ws + OFF_X);
  unsigned short* H1bf = (unsigned short*)(ws + OFF_H1);
  float*          bn1  = (float*)(ws + OFF_BN);
  float*          bn2  = bn1 + 128;
  float*          h2   = bn1 + 256;   // B*D floats right after accums

  hipMemsetAsync((void*)bn1, 0, 1024, stream);   // zero BN accumulators

  k12_gatt<<<Bb, 256, 0, stream>>>(hrt, neb, nebr, entW, relW, attW, attb,
                                   Ybf, out);
  k3_gemm<<<(Bb * CC) / 128, 256, 0, stream>>>(Ybf, gcnW, gcnb, Xbf);
  k4_adj<<<Bb, 128, 0, stream>>>(Xbf, adj, H1bf, bn1);
  k6_row0<<<Bb, 128, 0, stream>>>(H1bf, adj, bn1, gamma, beta, h2, bn2);
  k8_final<<<(Bb * DD) / 256, 256, 0, stream>>>(h2, bn2, gamma, beta, out);
}